// Round 4
// baseline (1046.368 us; speedup 1.0000x reference)
//
#include <hip/hip_runtime.h>
#include <math.h>

// Instant-NGP hash grid encoder, MI355X. Round 4: level-phased execution.
//
// Round-3 counters: FETCH_SIZE 3.0 GB, VALUBusy 3.9%, occupancy 88% ->
// bound on line-granular L2-miss traffic (all 16 levels' slices = 40 MB
// hot set vs 4 MB per-XCD L2). Fix: co-resident persistent grid sweeping
// levels in lockstep (level-outer loop), so each XCD's L2 holds exactly
// one 4 MB level slice at a time. Outputs go coalesced to a transposed
// scratch [L][N] in d_ws; a second streaming kernel transposes to [N][L].

#define LEVELS 16
#define LOG2_T 19
#define TMASK ((1u << LOG2_T) - 1u)

typedef float f32x2 __attribute__((ext_vector_type(2)));
typedef float f32x4 __attribute__((ext_vector_type(4)));

struct ResArgs { float r[LEVELS]; };

#define GATHER_BLOCKS 2048u   // 8 blocks/CU x 256 CUs -> fully co-resident

__device__ __forceinline__ f32x2 encode_one(
    const f32x2* __restrict__ tbl, float rf,
    float x0, float x1, float x2)
{
    // Same fp32 op chain as the reference (bit-identical to round-3 kernel).
    const float sx = x0 * rf, sy = x1 * rf, sz = x2 * rf;
    const float px = floorf(sx), py = floorf(sy), pz = floorf(sz);
    const float fx = sx - px, fy = sy - py, fz = sz - pz;
    const unsigned ix = (unsigned)px, iy = (unsigned)py, iz = (unsigned)pz;

    const unsigned hx0 = ix;
    const unsigned hx1 = ix + 1u;
    const unsigned hy0 = iy * 2654435761u;
    const unsigned hy1 = hy0 + 2654435761u;
    const unsigned hz0 = iz * 805459861u;
    const unsigned hz1 = hz0 + 805459861u;

    const unsigned i000 = (hx0 ^ hy0 ^ hz0) & TMASK;
    const unsigned i100 = (hx1 ^ hy0 ^ hz0) & TMASK;
    const unsigned i010 = (hx0 ^ hy1 ^ hz0) & TMASK;
    const unsigned i110 = (hx1 ^ hy1 ^ hz0) & TMASK;
    const unsigned i001 = (hx0 ^ hy0 ^ hz1) & TMASK;
    const unsigned i101 = (hx1 ^ hy0 ^ hz1) & TMASK;
    const unsigned i011 = (hx0 ^ hy1 ^ hz1) & TMASK;
    const unsigned i111 = (hx1 ^ hy1 ^ hz1) & TMASK;

    const f32x2 c000 = tbl[i000];
    const f32x2 c100 = tbl[i100];
    const f32x2 c010 = tbl[i010];
    const f32x2 c110 = tbl[i110];
    const f32x2 c001 = tbl[i001];
    const f32x2 c101 = tbl[i101];
    const f32x2 c011 = tbl[i011];
    const f32x2 c111 = tbl[i111];

    const float wx1 = fx, wx0 = 1.0f - fx;
    const float wy1 = fy, wy0 = 1.0f - fy;
    const float wz1 = fz, wz0 = 1.0f - fz;
    const float w00 = wy0 * wz0;
    const float w10 = wy1 * wz0;
    const float w01 = wy0 * wz1;
    const float w11 = wy1 * wz1;

    float w, a0, a1;
    w = wx0 * w00; a0 = w * c000.x;          a1 = w * c000.y;
    w = wx1 * w00; a0 = fmaf(w, c100.x, a0); a1 = fmaf(w, c100.y, a1);
    w = wx0 * w10; a0 = fmaf(w, c010.x, a0); a1 = fmaf(w, c010.y, a1);
    w = wx1 * w10; a0 = fmaf(w, c110.x, a0); a1 = fmaf(w, c110.y, a1);
    w = wx0 * w01; a0 = fmaf(w, c001.x, a0); a1 = fmaf(w, c001.y, a1);
    w = wx1 * w01; a0 = fmaf(w, c101.x, a0); a1 = fmaf(w, c101.y, a1);
    w = wx0 * w11; a0 = fmaf(w, c011.x, a0); a1 = fmaf(w, c011.y, a1);
    w = wx1 * w11; a0 = fmaf(w, c111.x, a0); a1 = fmaf(w, c111.y, a1);

    f32x2 o; o.x = a0; o.y = a1;
    return o;
}

// ---- Phase-coherent gather: level-outer sweep, transposed output --------
__global__ __launch_bounds__(256, 8) void ngp_gather_phased(
    const float* __restrict__ x,
    const float* __restrict__ table,
    f32x2* __restrict__ out_t,     // [LEVELS][n] scratch
    ResArgs res,
    unsigned n)
{
    const unsigned tid = blockIdx.x * 256u + threadIdx.x;
    const unsigned stride = GATHER_BLOCKS * 256u;   // 524288
    const unsigned p0 = tid;
    const unsigned p1 = tid + stride;
    const bool v0 = p0 < n, v1 = p1 < n;

    // Preload both points' coords into registers so x is read exactly once
    // (re-reading 12 MB of x per level would thrash the 4 MB level slice
    // out of the XCD L2).
    float a0 = 0.f, a1 = 0.f, a2 = 0.f, b0 = 0.f, b1 = 0.f, b2 = 0.f;
    if (v0) { a0 = x[3u*p0]; a1 = x[3u*p0+1u]; a2 = x[3u*p0+2u]; }
    if (v1) { b0 = x[3u*p1]; b1 = x[3u*p1+1u]; b2 = x[3u*p1+2u]; }

    #pragma unroll 1   // keep levels strictly sequential (the whole point)
    for (int l = 0; l < LEVELS; ++l) {
        const float rf = res.r[l];
        const f32x2* __restrict__ tbl =
            (const f32x2*)table + ((size_t)l << LOG2_T);
        if (v0) {
            f32x2 o = encode_one(tbl, rf, a0, a1, a2);
            __builtin_nontemporal_store(o, &out_t[(size_t)l * n + p0]);
        }
        if (v1) {
            f32x2 o = encode_one(tbl, rf, b0, b1, b2);
            __builtin_nontemporal_store(o, &out_t[(size_t)l * n + p1]);
        }
        __syncthreads();   // keep the block's waves phase-locked per level
    }
}

// ---- Streaming transpose: [L][N] -> [N][L], register-held --------------
__global__ __launch_bounds__(256) void ngp_transpose(
    const f32x2* __restrict__ out_t,
    f32x4* __restrict__ out,       // viewed as [n][8] f32x4
    unsigned n)
{
    const unsigned p = blockIdx.x * 256u + threadIdx.x;
    if (p >= n) return;
    f32x2 v[LEVELS];
    #pragma unroll
    for (int l = 0; l < LEVELS; ++l)
        v[l] = out_t[(size_t)l * n + p];          // coalesced per level
    #pragma unroll
    for (int j = 0; j < LEVELS / 2; ++j) {        // 8 x 16 B contiguous
        f32x4 q; q.x = v[2*j].x; q.y = v[2*j].y; q.z = v[2*j+1].x; q.w = v[2*j+1].y;
        __builtin_nontemporal_store(q, &out[(size_t)p * (LEVELS/2) + j]);
    }
}

// ---- Fallback (proven round-3 kernel): direct point-major ---------------
__global__ __launch_bounds__(256) void ngp_encode_direct(
    const float* __restrict__ x,
    const float* __restrict__ table,
    f32x2* __restrict__ out,
    ResArgs res,
    unsigned n_points)
{
    const unsigned t = blockIdx.x * 256u + threadIdx.x;
    const unsigned level = t & (LEVELS - 1u);
    const unsigned p = t >> 4;
    if (p >= n_points) return;
    const float x0 = x[3u*p], x1 = x[3u*p+1u], x2 = x[3u*p+2u];
    const f32x2* __restrict__ tbl =
        (const f32x2*)table + ((size_t)level << LOG2_T);
    f32x2 o = encode_one(tbl, res.r[level], x0, x1, x2);
    __builtin_nontemporal_store(o, &out[t]);
}

extern "C" void kernel_launch(void* const* d_in, const int* in_sizes, int n_in,
                              void* d_out, int out_size, void* d_ws, size_t ws_size,
                              hipStream_t stream) {
    const float* x     = (const float*)d_in[0];
    const float* table = (const float*)d_in[1];
    const unsigned n_points = (unsigned)(in_sizes[0] / 3);

    // numpy RES replication (same host libm): scale = 2^(1/3) chain.
    ResArgs res;
    const double scale = exp((log(512.0) - log(16.0)) / 15.0);
    for (int l = 0; l < LEVELS; ++l) {
        res.r[l] = (float)floor(16.0 * pow(scale, (double)l));
    }

    const size_t scratch_needed = (size_t)LEVELS * n_points * sizeof(f32x2);
    const bool fits = (ws_size >= scratch_needed) &&
                      (n_points <= 2u * GATHER_BLOCKS * 256u);

    if (fits) {
        f32x2* out_t = (f32x2*)d_ws;
        ngp_gather_phased<<<dim3(GATHER_BLOCKS), dim3(256), 0, stream>>>(
            x, table, out_t, res, n_points);
        const unsigned tblk = (n_points + 255u) / 256u;
        ngp_transpose<<<dim3(tblk), dim3(256), 0, stream>>>(
            out_t, (f32x4*)d_out, n_points);
    } else {
        const unsigned total = n_points * LEVELS;
        const unsigned nblk = (total + 255u) / 256u;
        ngp_encode_direct<<<dim3(nblk), dim3(256), 0, stream>>>(
            x, table, (f32x2*)d_out, res, n_points);
    }
}